// Round 2
// baseline (577.694 us; speedup 1.0000x reference)
//
#include <hip/hip_runtime.h>
#include <hip/hip_bf16.h>
#include <math.h>

// Problem: B=2, S=1024, D_MODEL=3072, HEADS=24, HEAD_DIM=128
#define B_   2
#define S_   1024
#define DM_  3072
#define H_   24
#define HD_  128
#define BH_  (B_*H_)          // 48
#define KDIM 3072             // K of both GEMMs
#define QSCALE 0.08838834764831845f   // 1/sqrt(128)

typedef __attribute__((ext_vector_type(8))) short short8;
typedef __attribute__((ext_vector_type(4))) float f32x4;

__device__ __forceinline__ unsigned short f2bf(float f) {
    union { float f; unsigned u; } v; v.f = f;
    unsigned r = v.u + 0x7fffu + ((v.u >> 16) & 1u);   // RNE
    return (unsigned short)(r >> 16);
}

// async 16B global -> LDS (wave-uniform lds base; HW scatters lane*16)
#define GLD_LDS16(gptr, ldsptr)                                                            \
    __builtin_amdgcn_global_load_lds(                                                      \
        (const __attribute__((address_space(1))) unsigned int*)(gptr),                     \
        (__attribute__((address_space(3))) unsigned int*)(ldsptr), 16, 0, 0)

// ---------------- merged fp32->bf16 conversion + rope table ----------------
// segments (in float4 units): hs(1572864) | Wq | Wk | Wv (2359296 ea) | Wo | rope(32768)
#define SEG0 1572864
#define SEGW 2359296
#define SB1  (SEG0 + SEGW)        // 3932160
#define SB2  (SB1 + SEGW)         // 6291456
#define SB3  (SB2 + SEGW)         // 8650752
#define SB4  (SB3 + SEGW)         // 11010048
#define SB5  (SB4 + 32768)        // 11042816
#define CVT_BLOCKS 43136          // SB5/256

__global__ __launch_bounds__(256) void cvt_all(const float* __restrict__ hs,
                                               const float* __restrict__ Wq,
                                               const float* __restrict__ Wk,
                                               const float* __restrict__ Wv,
                                               const float* __restrict__ Wo,
                                               const float* __restrict__ freqs,
                                               unsigned short* __restrict__ Xb,
                                               unsigned short* __restrict__ Wqkvb,
                                               unsigned short* __restrict__ Wob,
                                               float2* __restrict__ tab) {
    int i = blockIdx.x * 256 + threadIdx.x;
    const float* src;
    unsigned short* dst;
    int j;
    if (i < SEG0)      { src = hs; dst = Xb;              j = i; }
    else if (i < SB1)  { src = Wq; dst = Wqkvb;           j = i - SEG0; }
    else if (i < SB2)  { src = Wk; dst = Wqkvb + 9437184; j = i - SB1; }
    else if (i < SB3)  { src = Wv; dst = Wqkvb + 18874368; j = i - SB2; }
    else if (i < SB4)  { src = Wo; dst = Wob;             j = i - SB3; }
    else {
        j = i - SB4;               // rope: 32768 float4 of freqs
        float4 f = ((const float4*)freqs)[j];
        float4 lo = make_float4(cosf(f.x), sinf(f.x), cosf(f.y), sinf(f.y));
        float4 hi = make_float4(cosf(f.z), sinf(f.z), cosf(f.w), sinf(f.w));
        ((float4*)tab)[2 * j]     = lo;
        ((float4*)tab)[2 * j + 1] = hi;
        return;
    }
    float4 v = ((const float4*)src)[j];
    ushort4 o;
    o.x = f2bf(v.x); o.y = f2bf(v.y); o.z = f2bf(v.z); o.w = f2bf(v.w);
    ((ushort4*)dst)[j] = o;
}

// ---------------- GEMM: C[M,N] = A[M,K] * B[N,K]^T  (bf16 in) ----------------
// 128x128 tile, BK=64, 256 threads (4 waves, 64x64 each), 16x16x32 bf16 MFMA.
// Staging via global_load_lds width=16 with XOR chunk swizzle (conflict-free).
// B rows are PERMUTED at staging so that wave p=w&1 holds global cols
//   p=0: {0-31, 64-95}, p=1: {32-63, 96-127}
// -> each RoPE pair (d, d+64) lives in one lane (j and j+2).
// FUSED=1: N=9216 QKV projection; epilogue does RMSNorm+RoPE and writes
//   Qb,Kb (B,H,S,D bf16; Q pre-scaled 1/sqrt(128)) and Vtb (B,H,D,S bf16).
// FUSED=0: plain fp32 C-write (un-permuting columns).
template <int FUSED>
__global__ __launch_bounds__(256) void gemm_fused(const unsigned short* __restrict__ A,
                                                  const unsigned short* __restrict__ Bm,
                                                  float* __restrict__ C, int Ndim,
                                                  const float2* __restrict__ rtab,
                                                  const float* __restrict__ nqw,
                                                  const float* __restrict__ nkw,
                                                  unsigned short* __restrict__ Qb,
                                                  unsigned short* __restrict__ Kb,
                                                  unsigned short* __restrict__ Vtb) {
    __shared__ __align__(16) unsigned short As[128 * 64];
    __shared__ __align__(16) unsigned short Bs[128 * 64];
    __shared__ float pse[4][64];
    const int t = threadIdx.x;
    const int bx = blockIdx.x;
    const int m0 = blockIdx.y * 128, n0 = bx * 128;
    const int w = t >> 6, lane = t & 63, quad = lane >> 4, ln = lane & 15;
    const int wm = (w >> 1) * 64;
    const int p = w & 1;
    const int dj0 = p ? 32 : 0;
    const int rl = lane >> 3;             // row within 8-row staging group
    const int gc = (lane & 7) ^ rl;       // swizzled global chunk this lane fetches
    const int cs = ln & 7;                // read-side swizzle key
    const int woff = (w == 1) ? 32 : (w == 2) ? -32 : 0;   // B-row permutation

    f32x4 acc[4][4];
#pragma unroll
    for (int i = 0; i < 4; ++i)
#pragma unroll
        for (int j = 0; j < 4; ++j) acc[i][j] = (f32x4){0.f, 0.f, 0.f, 0.f};

    const unsigned short* ga = &A[(long long)(m0 + w * 32 + rl) * KDIM + gc * 8];
    const unsigned short* gb = &Bm[(long long)(n0 + w * 32 + woff + rl) * KDIM + gc * 8];

    for (int kt = 0; kt < KDIM / 64; ++kt) {
#pragma unroll
        for (int c = 0; c < 4; ++c) {
            const int r0 = w * 32 + c * 8;
            GLD_LDS16(ga + (long long)(c * 8) * KDIM, &As[r0 * 64]);
            GLD_LDS16(gb + (long long)(c * 8) * KDIM, &Bs[r0 * 64]);
        }
        ga += 64; gb += 64;
        __syncthreads();
#pragma unroll
        for (int ks = 0; ks < 2; ++ks) {
            short8 a[4], b[4];
#pragma unroll
            for (int i = 0; i < 4; ++i) {
                int row = wm + i * 16 + ln;
                a[i] = *(const short8*)&As[row * 64 + (((ks * 4 + quad) ^ cs) << 3)];
            }
#pragma unroll
            for (int j = 0; j < 4; ++j) {
                int row = p * 64 + j * 16 + ln;
                b[j] = *(const short8*)&Bs[row * 64 + (((ks * 4 + quad) ^ cs) << 3)];
            }
#pragma unroll
            for (int i = 0; i < 4; ++i)
#pragma unroll
                for (int j = 0; j < 4; ++j)
                    acc[i][j] = __builtin_amdgcn_mfma_f32_16x16x32_bf16(a[i], b[j], acc[i][j], 0, 0, 0);
        }
        __syncthreads();
    }

    // epilogue: row = m0+wm+i*16+quad*4+reg, col = n0+dj0+(j&1)*16+(j>>1)*64+ln
    if (!FUSED) {
#pragma unroll
        for (int i = 0; i < 4; ++i)
#pragma unroll
            for (int reg = 0; reg < 4; ++reg) {
                int row = m0 + wm + i * 16 + quad * 4 + reg;
                float* crow = C + (long long)row * Ndim + n0 + ln;
                crow[dj0]      = acc[i][0][reg];
                crow[dj0 + 16] = acc[i][1][reg];
                crow[dj0 + 64] = acc[i][2][reg];
                crow[dj0 + 80] = acc[i][3][reg];
            }
        return;
    }
    const int region = bx / 24;        // 0=Q, 1=K, 2=V (block-uniform)
    const int h = bx % 24;
    if (region < 2) {
#pragma unroll
        for (int i = 0; i < 4; ++i)
#pragma unroll
            for (int reg = 0; reg < 4; ++reg) {
                float s = 0.f;
#pragma unroll
                for (int j = 0; j < 4; ++j) { float v = acc[i][j][reg]; s += v * v; }
#pragma unroll
                for (int off = 8; off; off >>= 1) s += __shfl_xor(s, off, 16);
                if (ln == 0) pse[w][i * 16 + quad * 4 + reg] = s;
            }
        __syncthreads();
        const float* nw = region ? nkw : nqw;
        unsigned short* outp = region ? Kb : Qb;
        const float scl = region ? 1.f : QSCALE;
        const float nw0  = nw[dj0 + ln],      nw1  = nw[dj0 + 16 + ln];
        const float nw64 = nw[dj0 + 64 + ln], nw80 = nw[dj0 + 80 + ln];
#pragma unroll
        for (int i = 0; i < 4; ++i)
#pragma unroll
            for (int reg = 0; reg < 4; ++reg) {
                const int idx = i * 16 + quad * 4 + reg;
                const float tot = pse[w][idx] + pse[w ^ 1][idx];
                const float rr = rsqrtf(tot * (1.f / 128.f) + 1e-6f);
                const int row = m0 + wm + idx;
                const int b = row >> 10, s = row & 1023;
                const long long ob = ((long long)(b * H_ + h) * S_ + s) * HD_;
                {
                    const int d1 = dj0 + ln;
                    float y1 = acc[i][0][reg] * rr * nw0;
                    float y2 = acc[i][2][reg] * rr * nw64;
                    float2 c1 = rtab[s * HD_ + d1], c2 = rtab[s * HD_ + d1 + 64];
                    outp[ob + d1]      = f2bf((y1 * c1.x - y2 * c1.y) * scl);
                    outp[ob + d1 + 64] = f2bf((y2 * c2.x + y1 * c2.y) * scl);
                }
                {
                    const int d1 = dj0 + 16 + ln;
                    float y1 = acc[i][1][reg] * rr * nw1;
                    float y2 = acc[i][3][reg] * rr * nw80;
                    float2 c1 = rtab[s * HD_ + d1], c2 = rtab[s * HD_ + d1 + 64];
                    outp[ob + d1]      = f2bf((y1 * c1.x - y2 * c1.y) * scl);
                    outp[ob + d1 + 64] = f2bf((y2 * c2.x + y1 * c2.y) * scl);
                }
            }
    } else {
        // V: store transposed (B,H,D,S)
#pragma unroll
        for (int i = 0; i < 4; ++i)
#pragma unroll
            for (int reg = 0; reg < 4; ++reg) {
                const int row = m0 + wm + i * 16 + quad * 4 + reg;
                const int b = row >> 10, s = row & 1023;
                const long long vb = (long long)(b * H_ + h) * HD_;
#pragma unroll
                for (int j = 0; j < 4; ++j) {
                    const int d = dj0 + (j & 1) * 16 + (j >> 1) * 64 + ln;
                    Vtb[(vb + d) * S_ + s] = f2bf(acc[i][j][reg]);
                }
            }
    }
}

// ---------------- Flash attention (no-max softmax; scores bounded by ~11.32)
// grid (BH=48, S/64=16). 4 waves/block, each wave owns 16 Q rows.
// K/V fragments are read DIRECTLY FROM GLOBAL (L2-resident: per head K,V =
// 512 KB; all 16 q-tile blocks of a head land on one XCD since 48%8==0, so
// the per-XCD working set is 6 heads x 512 KB = 3 MB < 4 MB L2).
// No K/V LDS staging, no barriers; only the wave-private P roundtrip uses LDS.
__global__ __launch_bounds__(256) void attn(const unsigned short* __restrict__ Qb,
                                            const unsigned short* __restrict__ Kb,
                                            const unsigned short* __restrict__ Vtb,
                                            unsigned short* __restrict__ Ob) {
    __shared__ __align__(16) unsigned short Ps[4][16][72];   // per-wave P 16x64 (+8 pad)
    const int bh = blockIdx.x, qt = blockIdx.y;
    const int t = threadIdx.x, w = t >> 6, lane = t & 63, quad = lane >> 4, ln = lane & 15;
    const int b = bh / H_, h = bh - b * H_;

    short8 qfrag[4];
    const long long qbase = ((long long)bh * S_ + qt * 64 + w * 16 + ln) * HD_;
#pragma unroll
    for (int ks = 0; ks < 4; ++ks)
        qfrag[ks] = *(const short8*)&Qb[qbase + ks * 32 + quad * 8];

    f32x4 o[8];
#pragma unroll
    for (int n = 0; n < 8; ++n) o[n] = (f32x4){0.f, 0.f, 0.f, 0.f};
    float l_run[4] = {0.f, 0.f, 0.f, 0.f};

    const unsigned short* kp = Kb + (long long)bh * S_ * HD_;
    const unsigned short* vp = Vtb + (long long)bh * HD_ * S_;

    for (int kt = 0; kt < S_ / 64; ++kt) {
        const unsigned short* ktp = kp + (long long)kt * 64 * HD_;
        const unsigned short* vtp = vp + kt * 64;

        // S = Q K^T : B-fragment straight from global (16 rows x 64B windows)
        f32x4 sj[4];
        __builtin_amdgcn_s_setprio(1);
#pragma unroll
        for (int j = 0; j < 4; ++j) {
            f32x4 sa = (f32x4){0.f, 0.f, 0.f, 0.f};
#pragma unroll
            for (int ks = 0; ks < 4; ++ks) {
                short8 kb = *(const short8*)&ktp[(j * 16 + ln) * HD_ + ks * 32 + quad * 8];
                sa = __builtin_amdgcn_mfma_f32_16x16x32_bf16(qfrag[ks], kb, sa, 0, 0, 0);
            }
            sj[j] = sa;
        }
        __builtin_amdgcn_s_setprio(0);
        // softmax without max-subtraction (scores bounded); accumulate l
#pragma unroll
        for (int r = 0; r < 4; ++r) {
            float sum = 0.f;
#pragma unroll
            for (int j = 0; j < 4; ++j) {
                float p = __expf(sj[j][r]);
                sj[j][r] = p;
                sum += p;
            }
#pragma unroll
            for (int off = 8; off; off >>= 1) sum += __shfl_xor(sum, off, 16);
            l_run[r] += sum;
        }
        // P: C-layout -> LDS -> A-layout (wave-private, no barrier needed)
#pragma unroll
        for (int j = 0; j < 4; ++j)
#pragma unroll
            for (int r = 0; r < 4; ++r)
                Ps[w][quad * 4 + r][j * 16 + ln] = f2bf(sj[j][r]);
        __asm__ volatile("s_waitcnt lgkmcnt(0)" ::: "memory");
        // O += P V : V^T fragment straight from global (16 rows x 64B windows)
        __builtin_amdgcn_s_setprio(1);
#pragma unroll
        for (int ks = 0; ks < 2; ++ks) {
            short8 pf = *(const short8*)&Ps[w][ln][ks * 32 + quad * 8];
#pragma unroll
            for (int n = 0; n < 8; ++n) {
                short8 vf = *(const short8*)&vtp[(long long)(n * 16 + ln) * S_ + ks * 32 + quad * 8];
                o[n] = __builtin_amdgcn_mfma_f32_16x16x32_bf16(pf, vf, o[n], 0, 0, 0);
            }
        }
        __builtin_amdgcn_s_setprio(0);
    }

    float inv[4];
#pragma unroll
    for (int r = 0; r < 4; ++r) inv[r] = 1.f / l_run[r];
    const int row_s = qt * 64 + w * 16 + quad * 4;
#pragma unroll
    for (int n = 0; n < 8; ++n)
#pragma unroll
        for (int r = 0; r < 4; ++r) {
            long long off = ((long long)b * S_ + row_s + r) * DM_ + h * HD_ + n * 16 + ln;
            Ob[off] = f2bf(o[n][r] * inv[r]);
        }
}

// ---------------- host side ----------------
extern "C" void kernel_launch(void* const* d_in, const int* in_sizes, int n_in,
                              void* d_out, int out_size, void* d_ws, size_t ws_size,
                              hipStream_t stream) {
    const float* hs    = (const float*)d_in[0];
    const float* freqs = (const float*)d_in[1];
    const float* Wq    = (const float*)d_in[2];
    const float* Wk    = (const float*)d_in[3];
    const float* Wv    = (const float*)d_in[4];
    const float* Wo    = (const float*)d_in[5];
    const float* nqw   = (const float*)d_in[6];
    const float* nkw   = (const float*)d_in[7];
    float* out = (float*)d_out;

    char* ws = (char*)d_ws;
    unsigned short* Xb    = (unsigned short*)(ws);                   // 12,582,912
    unsigned short* Wqkvb = (unsigned short*)(ws + 12582912LL);      // 56,623,104 (Wq|Wk|Wv)
    unsigned short* Wob   = (unsigned short*)(ws + 69206016LL);      // 18,874,368
    unsigned short* Qb    = (unsigned short*)(ws + 88080384LL);      // 12,582,912 (B,H,S,D)
    unsigned short* Kb    = (unsigned short*)(ws + 100663296LL);     // 12,582,912 (B,H,S,D)
    unsigned short* Vtb   = (unsigned short*)(ws + 113246208LL);     // 12,582,912 (B,H,D,S)
    unsigned short* Ob    = (unsigned short*)(ws + 125829120LL);     // 12,582,912 (B,S,H*D)
    float2*         rtab  = (float2*)        (ws + 138412032LL);     // 1,048,576
    // total: 139,460,608 bytes

    // 1. all conversions + rope table in one launch
    cvt_all<<<CVT_BLOCKS, 256, 0, stream>>>(hs, Wq, Wk, Wv, Wo, freqs,
                                            Xb, Wqkvb, Wob, rtab);
    // 2. fused QKV projection + RMSNorm + RoPE + layout
    gemm_fused<1><<<dim3(72, 16), 256, 0, stream>>>(Xb, Wqkvb, nullptr, 0,
                                                    rtab, nqw, nkw, Qb, Kb, Vtb);
    // 3. flash attention (K/V direct from L2, no staging, no barriers)
    attn<<<dim3(BH_, S_ / 64), 256, 0, stream>>>(Qb, Kb, Vtb, Ob);
    // 4. output projection -> d_out fp32
    gemm_fused<0><<<dim3(24, 16), 256, 0, stream>>>(Ob, Wob, out, DM_,
                                                    nullptr, nullptr, nullptr,
                                                    nullptr, nullptr, nullptr);
}

// Round 3
// 575.195 us; speedup vs baseline: 1.0043x; 1.0043x over previous
//
#include <hip/hip_runtime.h>
#include <hip/hip_bf16.h>
#include <math.h>

// Problem: B=2, S=1024, D_MODEL=3072, HEADS=24, HEAD_DIM=128
#define B_   2
#define S_   1024
#define DM_  3072
#define H_   24
#define HD_  128
#define BH_  (B_*H_)          // 48
#define KDIM 3072             // K of both GEMMs
#define QSCALE 0.08838834764831845f   // 1/sqrt(128)

typedef __attribute__((ext_vector_type(8))) short short8;
typedef __attribute__((ext_vector_type(4))) float f32x4;

__device__ __forceinline__ unsigned short f2bf(float f) {
    union { float f; unsigned u; } v; v.f = f;
    unsigned r = v.u + 0x7fffu + ((v.u >> 16) & 1u);   // RNE
    return (unsigned short)(r >> 16);
}

// async 16B global -> LDS (wave-uniform lds base; HW scatters lane*16)
#define GLD_LDS16(gptr, ldsptr)                                                            \
    __builtin_amdgcn_global_load_lds(                                                      \
        (const __attribute__((address_space(1))) unsigned int*)(gptr),                     \
        (__attribute__((address_space(3))) unsigned int*)(ldsptr), 16, 0, 0)

// ---------------- merged fp32->bf16 conversion + rope table ----------------
// segments (in float4 units): hs(1572864) | Wq | Wk | Wv (2359296 ea) | Wo | rope(32768)
#define SEG0 1572864
#define SEGW 2359296
#define SB1  (SEG0 + SEGW)        // 3932160
#define SB2  (SB1 + SEGW)         // 6291456
#define SB3  (SB2 + SEGW)         // 8650752
#define SB4  (SB3 + SEGW)         // 11010048
#define SB5  (SB4 + 32768)        // 11042816
#define CVT_BLOCKS 43136          // SB5/256

__global__ __launch_bounds__(256) void cvt_all(const float* __restrict__ hs,
                                               const float* __restrict__ Wq,
                                               const float* __restrict__ Wk,
                                               const float* __restrict__ Wv,
                                               const float* __restrict__ Wo,
                                               const float* __restrict__ freqs,
                                               unsigned short* __restrict__ Xb,
                                               unsigned short* __restrict__ Wqkvb,
                                               unsigned short* __restrict__ Wob,
                                               float2* __restrict__ tab) {
    int i = blockIdx.x * 256 + threadIdx.x;
    const float* src;
    unsigned short* dst;
    int j;
    if (i < SEG0)      { src = hs; dst = Xb;              j = i; }
    else if (i < SB1)  { src = Wq; dst = Wqkvb;           j = i - SEG0; }
    else if (i < SB2)  { src = Wk; dst = Wqkvb + 9437184; j = i - SB1; }
    else if (i < SB3)  { src = Wv; dst = Wqkvb + 18874368; j = i - SB2; }
    else if (i < SB4)  { src = Wo; dst = Wob;             j = i - SB3; }
    else {
        j = i - SB4;               // rope: 32768 float4 of freqs
        float4 f = ((const float4*)freqs)[j];
        float4 lo = make_float4(cosf(f.x), sinf(f.x), cosf(f.y), sinf(f.y));
        float4 hi = make_float4(cosf(f.z), sinf(f.z), cosf(f.w), sinf(f.w));
        ((float4*)tab)[2 * j]     = lo;
        ((float4*)tab)[2 * j + 1] = hi;
        return;
    }
    float4 v = ((const float4*)src)[j];
    ushort4 o;
    o.x = f2bf(v.x); o.y = f2bf(v.y); o.z = f2bf(v.z); o.w = f2bf(v.w);
    ((ushort4*)dst)[j] = o;
}

// ---------------- GEMM: C[M,N] = A[M,K] * B[N,K]^T  (bf16 in) ----------------
// 128x128 tile, BK=64, 256 threads (4 waves, 64x64 each), 16x16x32 bf16 MFMA.
// Staging via global_load_lds width=16 with XOR chunk swizzle (conflict-free).
// B rows are PERMUTED at staging so that wave p=w&1 holds global cols
//   p=0: {0-31, 64-95}, p=1: {32-63, 96-127}
// -> each RoPE pair (d, d+64) lives in one lane (j and j+2).
// FUSED=1: N=9216 QKV projection; epilogue does RMSNorm+RoPE and writes
//   Qb,Kb (B,H,S,D bf16; Q pre-scaled 1/sqrt(128)) and Vtb (B,H,D,S bf16).
// FUSED=0: plain fp32 C-write (un-permuting columns).
template <int FUSED>
__global__ __launch_bounds__(256) void gemm_fused(const unsigned short* __restrict__ A,
                                                  const unsigned short* __restrict__ Bm,
                                                  float* __restrict__ C, int Ndim,
                                                  const float2* __restrict__ rtab,
                                                  const float* __restrict__ nqw,
                                                  const float* __restrict__ nkw,
                                                  unsigned short* __restrict__ Qb,
                                                  unsigned short* __restrict__ Kb,
                                                  unsigned short* __restrict__ Vtb) {
    __shared__ __align__(16) unsigned short As[128 * 64];
    __shared__ __align__(16) unsigned short Bs[128 * 64];
    __shared__ float pse[4][64];
    const int t = threadIdx.x;
    const int bx = blockIdx.x;
    const int m0 = blockIdx.y * 128, n0 = bx * 128;
    const int w = t >> 6, lane = t & 63, quad = lane >> 4, ln = lane & 15;
    const int wm = (w >> 1) * 64;
    const int p = w & 1;
    const int dj0 = p ? 32 : 0;
    const int rl = lane >> 3;             // row within 8-row staging group
    const int gc = (lane & 7) ^ rl;       // swizzled global chunk this lane fetches
    const int cs = ln & 7;                // read-side swizzle key
    const int woff = (w == 1) ? 32 : (w == 2) ? -32 : 0;   // B-row permutation

    f32x4 acc[4][4];
#pragma unroll
    for (int i = 0; i < 4; ++i)
#pragma unroll
        for (int j = 0; j < 4; ++j) acc[i][j] = (f32x4){0.f, 0.f, 0.f, 0.f};

    const unsigned short* ga = &A[(long long)(m0 + w * 32 + rl) * KDIM + gc * 8];
    const unsigned short* gb = &Bm[(long long)(n0 + w * 32 + woff + rl) * KDIM + gc * 8];

    for (int kt = 0; kt < KDIM / 64; ++kt) {
#pragma unroll
        for (int c = 0; c < 4; ++c) {
            const int r0 = w * 32 + c * 8;
            GLD_LDS16(ga + (long long)(c * 8) * KDIM, &As[r0 * 64]);
            GLD_LDS16(gb + (long long)(c * 8) * KDIM, &Bs[r0 * 64]);
        }
        ga += 64; gb += 64;
        __syncthreads();
#pragma unroll
        for (int ks = 0; ks < 2; ++ks) {
            short8 a[4], b[4];
#pragma unroll
            for (int i = 0; i < 4; ++i) {
                int row = wm + i * 16 + ln;
                a[i] = *(const short8*)&As[row * 64 + (((ks * 4 + quad) ^ cs) << 3)];
            }
#pragma unroll
            for (int j = 0; j < 4; ++j) {
                int row = p * 64 + j * 16 + ln;
                b[j] = *(const short8*)&Bs[row * 64 + (((ks * 4 + quad) ^ cs) << 3)];
            }
#pragma unroll
            for (int i = 0; i < 4; ++i)
#pragma unroll
                for (int j = 0; j < 4; ++j)
                    acc[i][j] = __builtin_amdgcn_mfma_f32_16x16x32_bf16(a[i], b[j], acc[i][j], 0, 0, 0);
        }
        __syncthreads();
    }

    // epilogue: row = m0+wm+i*16+quad*4+reg, col = n0+dj0+(j&1)*16+(j>>1)*64+ln
    if (!FUSED) {
#pragma unroll
        for (int i = 0; i < 4; ++i)
#pragma unroll
            for (int reg = 0; reg < 4; ++reg) {
                int row = m0 + wm + i * 16 + quad * 4 + reg;
                float* crow = C + (long long)row * Ndim + n0 + ln;
                crow[dj0]      = acc[i][0][reg];
                crow[dj0 + 16] = acc[i][1][reg];
                crow[dj0 + 64] = acc[i][2][reg];
                crow[dj0 + 80] = acc[i][3][reg];
            }
        return;
    }
    const int region = bx / 24;        // 0=Q, 1=K, 2=V (block-uniform)
    const int h = bx % 24;
    if (region < 2) {
#pragma unroll
        for (int i = 0; i < 4; ++i)
#pragma unroll
            for (int reg = 0; reg < 4; ++reg) {
                float s = 0.f;
#pragma unroll
                for (int j = 0; j < 4; ++j) { float v = acc[i][j][reg]; s += v * v; }
#pragma unroll
                for (int off = 8; off; off >>= 1) s += __shfl_xor(s, off, 16);
                if (ln == 0) pse[w][i * 16 + quad * 4 + reg] = s;
            }
        __syncthreads();
        const float* nw = region ? nkw : nqw;
        unsigned short* outp = region ? Kb : Qb;
        const float scl = region ? 1.f : QSCALE;
        const float nw0  = nw[dj0 + ln],      nw1  = nw[dj0 + 16 + ln];
        const float nw64 = nw[dj0 + 64 + ln], nw80 = nw[dj0 + 80 + ln];
#pragma unroll
        for (int i = 0; i < 4; ++i)
#pragma unroll
            for (int reg = 0; reg < 4; ++reg) {
                const int idx = i * 16 + quad * 4 + reg;
                const float tot = pse[w][idx] + pse[w ^ 1][idx];
                const float rr = rsqrtf(tot * (1.f / 128.f) + 1e-6f);
                const int row = m0 + wm + idx;
                const int b = row >> 10, s = row & 1023;
                const long long ob = ((long long)(b * H_ + h) * S_ + s) * HD_;
                {
                    const int d1 = dj0 + ln;
                    float y1 = acc[i][0][reg] * rr * nw0;
                    float y2 = acc[i][2][reg] * rr * nw64;
                    float2 c1 = rtab[s * HD_ + d1], c2 = rtab[s * HD_ + d1 + 64];
                    outp[ob + d1]      = f2bf((y1 * c1.x - y2 * c1.y) * scl);
                    outp[ob + d1 + 64] = f2bf((y2 * c2.x + y1 * c2.y) * scl);
                }
                {
                    const int d1 = dj0 + 16 + ln;
                    float y1 = acc[i][1][reg] * rr * nw1;
                    float y2 = acc[i][3][reg] * rr * nw80;
                    float2 c1 = rtab[s * HD_ + d1], c2 = rtab[s * HD_ + d1 + 64];
                    outp[ob + d1]      = f2bf((y1 * c1.x - y2 * c1.y) * scl);
                    outp[ob + d1 + 64] = f2bf((y2 * c2.x + y1 * c2.y) * scl);
                }
            }
    } else {
        // V: store transposed (B,H,D,S)
#pragma unroll
        for (int i = 0; i < 4; ++i)
#pragma unroll
            for (int reg = 0; reg < 4; ++reg) {
                const int row = m0 + wm + i * 16 + quad * 4 + reg;
                const int b = row >> 10, s = row & 1023;
                const long long vb = (long long)(b * H_ + h) * HD_;
#pragma unroll
                for (int j = 0; j < 4; ++j) {
                    const int d = dj0 + (j & 1) * 16 + (j >> 1) * 64 + ln;
                    Vtb[(vb + d) * S_ + s] = f2bf(acc[i][j][reg]);
                }
            }
    }
}

// ---------------- Flash attention (no-max softmax; scores bounded by ~11.32)
// grid (BH=48, S/64=16). 4 waves/block, each wave owns 16 Q rows.
// K/V read DIRECTLY FROM GLOBAL (L2-resident; FETCH_SIZE=18.5MB confirms).
// R2 diagnosis: VGPR=60 -> compiler kept only ~4 loads in flight -> ~8 exposed
// ~200cy L2 stalls per tile (MfmaUtil 5.6%). Fix: explicit fragment arrays
// kf[16]/vf[16] with static indices + sched_barrier(0) fences so all 16 loads
// of a batch issue before first use. V batch issues right after QK MFMAs; its
// first use is after softmax+P-roundtrip (~300cy of natural cover).
__global__ __launch_bounds__(256) void attn(const unsigned short* __restrict__ Qb,
                                            const unsigned short* __restrict__ Kb,
                                            const unsigned short* __restrict__ Vtb,
                                            unsigned short* __restrict__ Ob) {
    __shared__ __align__(16) unsigned short Ps[4][16][72];   // per-wave P 16x64 (+8 pad)
    const int bh = blockIdx.x, qt = blockIdx.y;
    const int t = threadIdx.x, w = t >> 6, lane = t & 63, quad = lane >> 4, ln = lane & 15;
    const int b = bh / H_, h = bh - b * H_;

    short8 qfrag[4];
    const long long qbase = ((long long)bh * S_ + qt * 64 + w * 16 + ln) * HD_;
#pragma unroll
    for (int ks = 0; ks < 4; ++ks)
        qfrag[ks] = *(const short8*)&Qb[qbase + ks * 32 + quad * 8];

    f32x4 o[8];
#pragma unroll
    for (int n = 0; n < 8; ++n) o[n] = (f32x4){0.f, 0.f, 0.f, 0.f};
    float l_run[4] = {0.f, 0.f, 0.f, 0.f};

    // per-lane base pointers (row/chunk offsets folded in)
    const unsigned short* kp = Kb + (long long)bh * S_ * HD_ + (long long)ln * HD_ + quad * 8;
    const unsigned short* vp = Vtb + (long long)bh * HD_ * S_ + (long long)ln * S_ + quad * 8;

    for (int kt = 0; kt < S_ / 64; ++kt) {
        const unsigned short* ktp = kp + (long long)kt * 64 * HD_;
        const unsigned short* vtp = vp + kt * 64;

        // batch-issue all 16 K fragments (row j*16+ln, chunk ks*32+quad*8)
        short8 kf[16];
#pragma unroll
        for (int j = 0; j < 4; ++j)
#pragma unroll
            for (int ks = 0; ks < 4; ++ks)
                kf[j * 4 + ks] = *(const short8*)&ktp[j * 16 * HD_ + ks * 32];
        __builtin_amdgcn_sched_barrier(0);   // pin: loads issue before MFMAs

        // S = Q K^T
        f32x4 sj[4];
        __builtin_amdgcn_s_setprio(1);
#pragma unroll
        for (int j = 0; j < 4; ++j) {
            f32x4 sa = (f32x4){0.f, 0.f, 0.f, 0.f};
#pragma unroll
            for (int ks = 0; ks < 4; ++ks)
                sa = __builtin_amdgcn_mfma_f32_16x16x32_bf16(qfrag[ks], kf[j * 4 + ks], sa, 0, 0, 0);
            sj[j] = sa;
        }
        __builtin_amdgcn_s_setprio(0);

        // batch-issue all 16 V^T fragments (row n*16+ln, chunk ks*32+quad*8);
        // first use is after softmax + P roundtrip -> latency hidden
        short8 vf[16];
#pragma unroll
        for (int ks = 0; ks < 2; ++ks)
#pragma unroll
            for (int n = 0; n < 8; ++n)
                vf[ks * 8 + n] = *(const short8*)&vtp[(long long)(n * 16) * S_ + ks * 32];
        __builtin_amdgcn_sched_barrier(0);   // pin: V loads issue before softmax

        // softmax without max-subtraction (scores bounded); accumulate l
#pragma unroll
        for (int r = 0; r < 4; ++r) {
            float sum = 0.f;
#pragma unroll
            for (int j = 0; j < 4; ++j) {
                float p = __expf(sj[j][r]);
                sj[j][r] = p;
                sum += p;
            }
#pragma unroll
            for (int off = 8; off; off >>= 1) sum += __shfl_xor(sum, off, 16);
            l_run[r] += sum;
        }
        // P: C-layout -> LDS -> A-layout (wave-private, no barrier needed)
#pragma unroll
        for (int j = 0; j < 4; ++j)
#pragma unroll
            for (int r = 0; r < 4; ++r)
                Ps[w][quad * 4 + r][j * 16 + ln] = f2bf(sj[j][r]);
        __asm__ volatile("s_waitcnt lgkmcnt(0)" ::: "memory");
        __builtin_amdgcn_sched_barrier(0);

        // O += P V
        __builtin_amdgcn_s_setprio(1);
#pragma unroll
        for (int ks = 0; ks < 2; ++ks) {
            short8 pf = *(const short8*)&Ps[w][ln][ks * 32 + quad * 8];
#pragma unroll
            for (int n = 0; n < 8; ++n)
                o[n] = __builtin_amdgcn_mfma_f32_16x16x32_bf16(pf, vf[ks * 8 + n], o[n], 0, 0, 0);
        }
        __builtin_amdgcn_s_setprio(0);
    }

    float inv[4];
#pragma unroll
    for (int r = 0; r < 4; ++r) inv[r] = 1.f / l_run[r];
    const int row_s = qt * 64 + w * 16 + quad * 4;
#pragma unroll
    for (int n = 0; n < 8; ++n)
#pragma unroll
        for (int r = 0; r < 4; ++r) {
            long long off = ((long long)b * S_ + row_s + r) * DM_ + h * HD_ + n * 16 + ln;
            Ob[off] = f2bf(o[n][r] * inv[r]);
        }
}

// ---------------- host side ----------------
extern "C" void kernel_launch(void* const* d_in, const int* in_sizes, int n_in,
                              void* d_out, int out_size, void* d_ws, size_t ws_size,
                              hipStream_t stream) {
    const float* hs    = (const float*)d_in[0];
    const float* freqs = (const float*)d_in[1];
    const float* Wq    = (const float*)d_in[2];
    const float* Wk    = (const float*)d_in[3];
    const float* Wv    = (const float*)d_in[4];
    const float* Wo    = (const float*)d_in[5];
    const float* nqw   = (const float*)d_in[6];
    const float* nkw   = (const float*)d_in[7];
    float* out = (float*)d_out;

    char* ws = (char*)d_ws;
    unsigned short* Xb    = (unsigned short*)(ws);                   // 12,582,912
    unsigned short* Wqkvb = (unsigned short*)(ws + 12582912LL);      // 56,623,104 (Wq|Wk|Wv)
    unsigned short* Wob   = (unsigned short*)(ws + 69206016LL);      // 18,874,368
    unsigned short* Qb    = (unsigned short*)(ws + 88080384LL);      // 12,582,912 (B,H,S,D)
    unsigned short* Kb    = (unsigned short*)(ws + 100663296LL);     // 12,582,912 (B,H,S,D)
    unsigned short* Vtb   = (unsigned short*)(ws + 113246208LL);     // 12,582,912 (B,H,D,S)
    unsigned short* Ob    = (unsigned short*)(ws + 125829120LL);     // 12,582,912 (B,S,H*D)
    float2*         rtab  = (float2*)        (ws + 138412032LL);     // 1,048,576
    // total: 139,460,608 bytes

    // 1. all conversions + rope table in one launch
    cvt_all<<<CVT_BLOCKS, 256, 0, stream>>>(hs, Wq, Wk, Wv, Wo, freqs,
                                            Xb, Wqkvb, Wob, rtab);
    // 2. fused QKV projection + RMSNorm + RoPE + layout
    gemm_fused<1><<<dim3(72, 16), 256, 0, stream>>>(Xb, Wqkvb, nullptr, 0,
                                                    rtab, nqw, nkw, Qb, Kb, Vtb);
    // 3. flash attention (K/V direct from L2, batched fragment loads)
    attn<<<dim3(BH_, S_ / 64), 256, 0, stream>>>(Qb, Kb, Vtb, Ob);
    // 4. output projection -> d_out fp32
    gemm_fused<0><<<dim3(24, 16), 256, 0, stream>>>(Ob, Wob, out, DM_,
                                                    nullptr, nullptr, nullptr,
                                                    nullptr, nullptr, nullptr);
}

// Round 5
// 458.060 us; speedup vs baseline: 1.2612x; 1.2557x over previous
//
#include <hip/hip_runtime.h>
#include <hip/hip_bf16.h>
#include <math.h>

// Problem: B=2, S=1024, D_MODEL=3072, HEADS=24, HEAD_DIM=128
#define B_   2
#define S_   1024
#define DM_  3072
#define H_   24
#define HD_  128
#define BH_  (B_*H_)          // 48
#define KDIM 3072             // K of both GEMMs
#define QSCALE 0.08838834764831845f   // 1/sqrt(128)

typedef __attribute__((ext_vector_type(8))) short short8;
typedef __attribute__((ext_vector_type(4))) short s16x4;
typedef __attribute__((ext_vector_type(4))) float f32x4;
typedef __attribute__((ext_vector_type(16))) float f32x16;
typedef __attribute__((ext_vector_type(4))) unsigned int u32x4;

__device__ __forceinline__ unsigned short f2bf(float f) {
    union { float f; unsigned u; } v; v.f = f;
    unsigned r = v.u + 0x7fffu + ((v.u >> 16) & 1u);   // RNE
    return (unsigned short)(r >> 16);
}

// pack two f32 -> two bf16 in one u32 (lo = a, hi = b), RNE
__device__ __forceinline__ unsigned cvtpk_bf16(float a, float b) {
    unsigned r;
    asm("v_cvt_pk_bf16_f32 %0, %1, %2" : "=v"(r) : "v"(a), "v"(b));
    return r;
}

// async 16B global -> LDS (wave-uniform lds base; HW scatters lane*16)
#define GLD_LDS16(gptr, ldsptr)                                                            \
    __builtin_amdgcn_global_load_lds(                                                      \
        (const __attribute__((address_space(1))) unsigned int*)(gptr),                     \
        (__attribute__((address_space(3))) unsigned int*)(ldsptr), 16, 0, 0)

// ---------------- merged fp32->bf16 conversion + rope table ----------------
#define SEG0 1572864
#define SEGW 2359296
#define SB1  (SEG0 + SEGW)        // 3932160
#define SB2  (SB1 + SEGW)         // 6291456
#define SB3  (SB2 + SEGW)         // 8650752
#define SB4  (SB3 + SEGW)         // 11010048
#define SB5  (SB4 + 32768)        // 11042816
#define CVT_BLOCKS 43136          // SB5/256

__global__ __launch_bounds__(256) void cvt_all(const float* __restrict__ hs,
                                               const float* __restrict__ Wq,
                                               const float* __restrict__ Wk,
                                               const float* __restrict__ Wv,
                                               const float* __restrict__ Wo,
                                               const float* __restrict__ freqs,
                                               unsigned short* __restrict__ Xb,
                                               unsigned short* __restrict__ Wqkvb,
                                               unsigned short* __restrict__ Wob,
                                               float2* __restrict__ tab) {
    int i = blockIdx.x * 256 + threadIdx.x;
    const float* src;
    unsigned short* dst;
    int j;
    if (i < SEG0)      { src = hs; dst = Xb;              j = i; }
    else if (i < SB1)  { src = Wq; dst = Wqkvb;           j = i - SEG0; }
    else if (i < SB2)  { src = Wk; dst = Wqkvb + 9437184; j = i - SB1; }
    else if (i < SB3)  { src = Wv; dst = Wqkvb + 18874368; j = i - SB2; }
    else if (i < SB4)  { src = Wo; dst = Wob;             j = i - SB3; }
    else {
        j = i - SB4;               // rope: 32768 float4 of freqs
        float4 f = ((const float4*)freqs)[j];
        float4 lo = make_float4(cosf(f.x), sinf(f.x), cosf(f.y), sinf(f.y));
        float4 hi = make_float4(cosf(f.z), sinf(f.z), cosf(f.w), sinf(f.w));
        ((float4*)tab)[2 * j]     = lo;
        ((float4*)tab)[2 * j + 1] = hi;
        return;
    }
    float4 v = ((const float4*)src)[j];
    ushort4 o;
    o.x = f2bf(v.x); o.y = f2bf(v.y); o.z = f2bf(v.z); o.w = f2bf(v.w);
    ((ushort4*)dst)[j] = o;
}

// ---------------- GEMM: C[M,N] = A[M,K] * B[N,K]^T  (bf16 in) ----------------
// (unchanged from the verified 177us / 0-conflict form)
template <int FUSED>
__global__ __launch_bounds__(256) void gemm_fused(const unsigned short* __restrict__ A,
                                                  const unsigned short* __restrict__ Bm,
                                                  float* __restrict__ C, int Ndim,
                                                  const float2* __restrict__ rtab,
                                                  const float* __restrict__ nqw,
                                                  const float* __restrict__ nkw,
                                                  unsigned short* __restrict__ Qb,
                                                  unsigned short* __restrict__ Kb,
                                                  unsigned short* __restrict__ Vtb) {
    __shared__ __align__(16) unsigned short As[128 * 64];
    __shared__ __align__(16) unsigned short Bs[128 * 64];
    __shared__ float pse[4][64];
    const int t = threadIdx.x;
    const int bx = blockIdx.x;
    const int m0 = blockIdx.y * 128, n0 = bx * 128;
    const int w = t >> 6, lane = t & 63, quad = lane >> 4, ln = lane & 15;
    const int wm = (w >> 1) * 64;
    const int p = w & 1;
    const int dj0 = p ? 32 : 0;
    const int rl = lane >> 3;
    const int gc = (lane & 7) ^ rl;
    const int cs = ln & 7;
    const int woff = (w == 1) ? 32 : (w == 2) ? -32 : 0;

    f32x4 acc[4][4];
#pragma unroll
    for (int i = 0; i < 4; ++i)
#pragma unroll
        for (int j = 0; j < 4; ++j) acc[i][j] = (f32x4){0.f, 0.f, 0.f, 0.f};

    const unsigned short* ga = &A[(long long)(m0 + w * 32 + rl) * KDIM + gc * 8];
    const unsigned short* gb = &Bm[(long long)(n0 + w * 32 + woff + rl) * KDIM + gc * 8];

    for (int kt = 0; kt < KDIM / 64; ++kt) {
#pragma unroll
        for (int c = 0; c < 4; ++c) {
            const int r0 = w * 32 + c * 8;
            GLD_LDS16(ga + (long long)(c * 8) * KDIM, &As[r0 * 64]);
            GLD_LDS16(gb + (long long)(c * 8) * KDIM, &Bs[r0 * 64]);
        }
        ga += 64; gb += 64;
        __syncthreads();
#pragma unroll
        for (int ks = 0; ks < 2; ++ks) {
            short8 a[4], b[4];
#pragma unroll
            for (int i = 0; i < 4; ++i) {
                int row = wm + i * 16 + ln;
                a[i] = *(const short8*)&As[row * 64 + (((ks * 4 + quad) ^ cs) << 3)];
            }
#pragma unroll
            for (int j = 0; j < 4; ++j) {
                int row = p * 64 + j * 16 + ln;
                b[j] = *(const short8*)&Bs[row * 64 + (((ks * 4 + quad) ^ cs) << 3)];
            }
#pragma unroll
            for (int i = 0; i < 4; ++i)
#pragma unroll
                for (int j = 0; j < 4; ++j)
                    acc[i][j] = __builtin_amdgcn_mfma_f32_16x16x32_bf16(a[i], b[j], acc[i][j], 0, 0, 0);
        }
        __syncthreads();
    }

    if (!FUSED) {
#pragma unroll
        for (int i = 0; i < 4; ++i)
#pragma unroll
            for (int reg = 0; reg < 4; ++reg) {
                int row = m0 + wm + i * 16 + quad * 4 + reg;
                float* crow = C + (long long)row * Ndim + n0 + ln;
                crow[dj0]      = acc[i][0][reg];
                crow[dj0 + 16] = acc[i][1][reg];
                crow[dj0 + 64] = acc[i][2][reg];
                crow[dj0 + 80] = acc[i][3][reg];
            }
        return;
    }
    const int region = bx / 24;        // 0=Q, 1=K, 2=V (block-uniform)
    const int h = bx % 24;
    if (region < 2) {
#pragma unroll
        for (int i = 0; i < 4; ++i)
#pragma unroll
            for (int reg = 0; reg < 4; ++reg) {
                float s = 0.f;
#pragma unroll
                for (int j = 0; j < 4; ++j) { float v = acc[i][j][reg]; s += v * v; }
#pragma unroll
                for (int off = 8; off; off >>= 1) s += __shfl_xor(s, off, 16);
                if (ln == 0) pse[w][i * 16 + quad * 4 + reg] = s;
            }
        __syncthreads();
        const float* nw = region ? nkw : nqw;
        unsigned short* outp = region ? Kb : Qb;
        const float scl = region ? 1.f : QSCALE;
        const float nw0  = nw[dj0 + ln],      nw1  = nw[dj0 + 16 + ln];
        const float nw64 = nw[dj0 + 64 + ln], nw80 = nw[dj0 + 80 + ln];
#pragma unroll
        for (int i = 0; i < 4; ++i)
#pragma unroll
            for (int reg = 0; reg < 4; ++reg) {
                const int idx = i * 16 + quad * 4 + reg;
                const float tot = pse[w][idx] + pse[w ^ 1][idx];
                const float rr = rsqrtf(tot * (1.f / 128.f) + 1e-6f);
                const int row = m0 + wm + idx;
                const int b = row >> 10, s = row & 1023;
                const long long ob = ((long long)(b * H_ + h) * S_ + s) * HD_;
                {
                    const int d1 = dj0 + ln;
                    float y1 = acc[i][0][reg] * rr * nw0;
                    float y2 = acc[i][2][reg] * rr * nw64;
                    float2 c1 = rtab[s * HD_ + d1], c2 = rtab[s * HD_ + d1 + 64];
                    outp[ob + d1]      = f2bf((y1 * c1.x - y2 * c1.y) * scl);
                    outp[ob + d1 + 64] = f2bf((y2 * c2.x + y1 * c2.y) * scl);
                }
                {
                    const int d1 = dj0 + 16 + ln;
                    float y1 = acc[i][1][reg] * rr * nw1;
                    float y2 = acc[i][3][reg] * rr * nw80;
                    float2 c1 = rtab[s * HD_ + d1], c2 = rtab[s * HD_ + d1 + 64];
                    outp[ob + d1]      = f2bf((y1 * c1.x - y2 * c1.y) * scl);
                    outp[ob + d1 + 64] = f2bf((y2 * c2.x + y1 * c2.y) * scl);
                }
            }
    } else {
        // V: store transposed (B,H,D,S)
#pragma unroll
        for (int i = 0; i < 4; ++i)
#pragma unroll
            for (int reg = 0; reg < 4; ++reg) {
                const int row = m0 + wm + i * 16 + quad * 4 + reg;
                const int b = row >> 10, s = row & 1023;
                const long long vb = (long long)(b * H_ + h) * HD_;
#pragma unroll
                for (int j = 0; j < 4; ++j) {
                    const int d = dj0 + (j & 1) * 16 + (j >> 1) * 64 + ln;
                    Vtb[(vb + d) * S_ + s] = f2bf(acc[i][j][reg]);
                }
            }
    }
}

// ---------------- Flash attention, m214-style structure ----------------
// 32x32x16 MFMA, SWAPPED QK^T (S^T = mfma(K, Q)) so each lane owns the full
// P-row of one q (q = lane&31; keys split across half = lane>>5).
// Softmax fully in-register: 1 shfl_xor(32) for the l-sum (vs 16-deep trees),
// NO P LDS roundtrip (cvt_pk pack + shfl_xor(32) half-exchange builds the
// PV B-fragment in registers). O accumulated TRANSPOSED (O^T[d][q]), written
// via a one-time LDS bounce in the epilogue.
// grid (48, 8): 4 waves/block, wave = 32 q-rows, block = 128 q-rows.
// K/V double-buffered in LDS (gld_lds + XOR chunk swizzle), 1 barrier/tile.
// C/D layout (guide-verified): col = lane&31, row = (reg&3)+8*(reg>>2)+4*half.
__global__ __launch_bounds__(256) void attn(const unsigned short* __restrict__ Qb,
                                            const unsigned short* __restrict__ Kb,
                                            const unsigned short* __restrict__ Vtb,
                                            unsigned short* __restrict__ Ob) {
    // Ks[2]: 2 x 64x128 = 2 x 8192 shorts;  Vts[2]: 2 x 128x64 = 2 x 8192
    // epilogue reuses the whole region as Osm[4][32][132]
    __shared__ __align__(16) unsigned short shm[32768];
    const int bh = blockIdx.x, qt = blockIdx.y;
    const int t = threadIdx.x, w = t >> 6, lane = t & 63;
    const int q5 = lane & 31, half = lane >> 5;
    const int b = bh / H_, h = bh - b * H_;

    // Q fragment = B-operand of swapped QK^T: B[k=d][col=q]
    // lane needs Q[q5][dc*16 + half*8 + e], e=0..7 -> 16B contiguous
    const long long qrow = (long long)bh * S_ + qt * 128 + w * 32 + q5;
    short8 qf[8];
#pragma unroll
    for (int dc = 0; dc < 8; ++dc)
        qf[dc] = *(const short8*)&Qb[qrow * HD_ + dc * 16 + half * 8];

    f32x16 o[4];
#pragma unroll
    for (int dt = 0; dt < 4; ++dt)
#pragma unroll
        for (int r = 0; r < 16; ++r) o[dt][r] = 0.f;
    float l_run = 0.f;

    const long long kbase = (long long)bh * S_ * HD_;
    const long long vbase = (long long)bh * HD_ * S_;
    const int krl = lane >> 4, ksl = lane & 15;   // K staging: 4 rows x 16 slots
    const int vrl = lane >> 3, vsl = lane & 7;    // V staging: 8 rows x 8 slots

#define ATTN_STAGE(buf, ktile) do {                                                         \
    _Pragma("unroll")                                                                       \
    for (int c = 0; c < 4; ++c) {                                                           \
        const int rk = c * 16 + w * 4 + krl;                                                \
        GLD_LDS16(&Kb[kbase + (long long)((ktile) * 64 + rk) * HD_ + (ksl ^ (rk & 15)) * 8],\
                  &shm[(buf) * 8192 + (c * 16 + w * 4) * 128]);                             \
        const int rv = c * 32 + w * 8 + vrl;                                                \
        GLD_LDS16(&Vtb[vbase + (long long)rv * S_ + (ktile) * 64 + (vsl ^ (rv & 7)) * 8],   \
                  &shm[16384 + (buf) * 8192 + (c * 32 + w * 8) * 64]);                      \
    } } while (0)

    ATTN_STAGE(0, 0);
    __syncthreads();

    for (int kt = 0; kt < S_ / 64; ++kt) {
        const int cur = kt & 1;
        if (kt + 1 < S_ / 64) ATTN_STAGE(cur ^ 1, kt + 1);
        const unsigned short* Kc = &shm[cur * 8192];
        const unsigned short* Vc = &shm[16384 + cur * 8192];

        // ---- S^T = K x Q^T : two 32-key blocks, accumulate over 8 d-chunks
        f32x16 st0, st1;
#pragma unroll
        for (int r = 0; r < 16; ++r) { st0[r] = 0.f; st1[r] = 0.f; }
        __builtin_amdgcn_s_setprio(1);
#pragma unroll
        for (int dc = 0; dc < 8; ++dc) {
            const int sl = ((dc * 2 + half) ^ (q5 & 15)) * 8;
            short8 kf0 = *(const short8*)&Kc[q5 * 128 + sl];
            short8 kf1 = *(const short8*)&Kc[(32 + q5) * 128 + sl];
            st0 = __builtin_amdgcn_mfma_f32_32x32x16_bf16(kf0, qf[dc], st0, 0, 0, 0);
            st1 = __builtin_amdgcn_mfma_f32_32x32x16_bf16(kf1, qf[dc], st1, 0, 0, 0);
        }
        __builtin_amdgcn_s_setprio(0);

        // ---- softmax (no-max; scores bounded): exp in place, in-register sum
#pragma unroll
        for (int r = 0; r < 16; ++r) { st0[r] = __expf(st0[r]); st1[r] = __expf(st1[r]); }
        {
            float s0 = 0.f, s1 = 0.f, s2 = 0.f, s3 = 0.f;
#pragma unroll
            for (int r = 0; r < 16; r += 4) {
                s0 += st0[r]; s1 += st0[r + 1]; s2 += st0[r + 2]; s3 += st0[r + 3];
                s0 += st1[r]; s1 += st1[r + 1]; s2 += st1[r + 2]; s3 += st1[r + 3];
            }
            float sum = (s0 + s1) + (s2 + s3);
            sum += __shfl_xor(sum, 32);
            l_run += sum;
        }

        // ---- pack P -> bf16 pairs; exchange halves so each lane can build
        //      the PV B-fragment (keys kc*16 + half*8 + 0..7) in registers
        unsigned pk0[8], pk1[8], pq0[8], pq1[8];
#pragma unroll
        for (int rp = 0; rp < 8; ++rp) {
            pk0[rp] = cvtpk_bf16(st0[2 * rp], st0[2 * rp + 1]);
            pk1[rp] = cvtpk_bf16(st1[2 * rp], st1[2 * rp + 1]);
        }
#pragma unroll
        for (int rp = 0; rp < 8; ++rp) {
            pq0[rp] = (unsigned)__shfl_xor((int)pk0[rp], 32);
            pq1[rp] = (unsigned)__shfl_xor((int)pk1[rp], 32);
        }

        // ---- O^T += V^T x P^T  (A = V^T from LDS, B = P^T assembled above)
#define PVSTEP(kc, PK, PQ, c1)                                                              \
        {                                                                                   \
            unsigned u0 = half ? PQ[4 * c1 + 2] : PK[4 * c1 + 0];                           \
            unsigned u1 = half ? PQ[4 * c1 + 3] : PK[4 * c1 + 1];                           \
            unsigned u2 = half ? PK[4 * c1 + 2] : PQ[4 * c1 + 0];                           \
            unsigned u3 = half ? PK[4 * c1 + 3] : PQ[4 * c1 + 1];                           \
            u32x4 uu = {u0, u1, u2, u3};                                                    \
            short8 pf = __builtin_bit_cast(short8, uu);                                     \
            _Pragma("unroll")                                                               \
            for (int dt = 0; dt < 4; ++dt) {                                                \
                const int rv = dt * 32 + q5;                                                \
                short8 vf = *(const short8*)&Vc[rv * 64 + (((kc * 2 + half) ^ (rv & 7)) * 8)];\
                o[dt] = __builtin_amdgcn_mfma_f32_32x32x16_bf16(vf, pf, o[dt], 0, 0, 0);    \
            }                                                                               \
        }
        __builtin_amdgcn_s_setprio(1);
        PVSTEP(0, pk0, pq0, 0)
        PVSTEP(1, pk0, pq0, 1)
        PVSTEP(2, pk1, pq1, 0)
        PVSTEP(3, pk1, pq1, 1)
        __builtin_amdgcn_s_setprio(0);
#undef PVSTEP
        __syncthreads();   // next buf staged+drained; cur reusable
    }
#undef ATTN_STAGE

    // ---- epilogue: normalize, transpose via LDS bounce, coalesced store
    const float inv = 1.f / l_run;
    const int obase = w * 32 * 132;     // per-wave Osm region [32 q][132 d]
#pragma unroll
    for (int dt = 0; dt < 4; ++dt)
#pragma unroll
        for (int rp = 0; rp < 8; ++rp) {
            const int d = dt * 32 + ((2 * rp) & 3) + 8 * (rp >> 1) + 4 * half;
            unsigned pair = cvtpk_bf16(o[dt][2 * rp] * inv, o[dt][2 * rp + 1] * inv);
            *(unsigned*)&shm[obase + q5 * 132 + d] = pair;
        }
    __asm__ volatile("s_waitcnt lgkmcnt(0)" ::: "memory");
#pragma unroll
    for (int it = 0; it < 8; ++it) {
        const int q  = (it & 3) * 8 + (lane >> 3);
        const int ch = (it >> 2) * 8 + (lane & 7);
        s16x4 lo = *(const s16x4*)&shm[obase + q * 132 + ch * 8];
        s16x4 hi = *(const s16x4*)&shm[obase + q * 132 + ch * 8 + 4];
        const long long oaddr = ((long long)(b * S_ + qt * 128 + w * 32 + q)) * DM_ + h * HD_ + ch * 8;
        *(s16x4*)&Ob[oaddr]     = lo;
        *(s16x4*)&Ob[oaddr + 4] = hi;
    }
}

// ---------------- host side ----------------
extern "C" void kernel_launch(void* const* d_in, const int* in_sizes, int n_in,
                              void* d_out, int out_size, void* d_ws, size_t ws_size,
                              hipStream_t stream) {
    const float* hs    = (const float*)d_in[0];
    const float* freqs = (const float*)d_in[1];
    const float* Wq    = (const float*)d_in[2];
    const float* Wk    = (const float*)d_in[3];
    const float* Wv    = (const float*)d_in[4];
    const float* Wo    = (const float*)d_in[5];
    const float* nqw   = (const float*)d_in[6];
    const float* nkw   = (const float*)d_in[7];
    float* out = (float*)d_out;

    char* ws = (char*)d_ws;
    unsigned short* Xb    = (unsigned short*)(ws);                   // 12,582,912
    unsigned short* Wqkvb = (unsigned short*)(ws + 12582912LL);      // 56,623,104 (Wq|Wk|Wv)
    unsigned short* Wob   = (unsigned short*)(ws + 69206016LL);      // 18,874,368
    unsigned short* Qb    = (unsigned short*)(ws + 88080384LL);      // 12,582,912 (B,H,S,D)
    unsigned short* Kb    = (unsigned short*)(ws + 100663296LL);     // 12,582,912 (B,H,S,D)
    unsigned short* Vtb   = (unsigned short*)(ws + 113246208LL);     // 12,582,912 (B,H,D,S)
    unsigned short* Ob    = (unsigned short*)(ws + 125829120LL);     // 12,582,912 (B,S,H*D)
    float2*         rtab  = (float2*)        (ws + 138412032LL);     // 1,048,576
    // total: 139,460,608 bytes

    // 1. all conversions + rope table in one launch
    cvt_all<<<CVT_BLOCKS, 256, 0, stream>>>(hs, Wq, Wk, Wv, Wo, freqs,
                                            Xb, Wqkvb, Wob, rtab);
    // 2. fused QKV projection + RMSNorm + RoPE + layout
    gemm_fused<1><<<dim3(72, 16), 256, 0, stream>>>(Xb, Wqkvb, nullptr, 0,
                                                    rtab, nqw, nkw, Qb, Kb, Vtb);
    // 3. flash attention (32x32 swapped-QK structure, in-register softmax)
    attn<<<dim3(BH_, S_ / 128), 256, 0, stream>>>(Qb, Kb, Vtb, Ob);
    // 4. output projection -> d_out fp32
    gemm_fused<0><<<dim3(24, 16), 256, 0, stream>>>(Ob, Wob, out, DM_,
                                                    nullptr, nullptr, nullptr,
                                                    nullptr, nullptr, nullptr);
}